// Round 17
// baseline (239.834 us; speedup 1.0000x reference)
//
#include <hip/hip_runtime.h>
#include <stdint.h>

#define BATCH 8
#define NPTS 4096
#define NS 1024
#define KD 6   // sorted-list depth (rows and cols)

typedef unsigned long long u64;
typedef unsigned int u32;
typedef unsigned short u16;
typedef unsigned char u8;

#define DEADV (~0ull)
#define QNANB 0x7FC00000u
// key: [51:20]=f32 dist bits, [19:10]=row, [9:0]=col. u64 order == (dist,row,col)
// lexicographic == JAX row-major argmin tie-break. Keys unique per (row,col).
// NaN dist bits sort above all finite distances -> dead coords auto-lose.

__device__ __forceinline__ float pdist3(float ax, float ay, float az,
                                        float bx, float by, float bz) {
    float dx = ax - bx, dy = ay - by, dz = az - bz;
    float d2 = __fmaf_rn(dz, dz, __fmaf_rn(dy, dy, dx * dx));
    return __fsqrt_rn(d2);
}

__device__ __forceinline__ u64 packv(float d, u32 row, u32 col) {
    return ((u64)__float_as_uint(d) << 20) | ((u64)row << 10) | (u64)col;
}

__device__ __forceinline__ u64 u64min2(u64 a, u64 b) { return a < b ? a : b; }
__device__ __forceinline__ u64 u64max2(u64 a, u64 b) { return a > b ? a : b; }

__device__ __forceinline__ u64 tree16(const u64* p) {
    u64 a0 = u64min2(p[0], p[1]),   a1 = u64min2(p[2], p[3]);
    u64 a2 = u64min2(p[4], p[5]),   a3 = u64min2(p[6], p[7]);
    u64 a4 = u64min2(p[8], p[9]),   a5 = u64min2(p[10], p[11]);
    u64 a6 = u64min2(p[12], p[13]), a7 = u64min2(p[14], p[15]);
    u64 b0 = u64min2(a0, a1), b1 = u64min2(a2, a3);
    u64 b2 = u64min2(a4, a5), b3 = u64min2(a6, a7);
    return u64min2(u64min2(b0, b1), u64min2(b2, b3));
}

template<int CTRL>
__device__ __forceinline__ u64 dpp_min_step(u64 m) {
    u32 lo = (u32)m, hi = (u32)(m >> 32);
    u32 olo = (u32)__builtin_amdgcn_update_dpp(-1, (int)lo, CTRL, 0xF, 0xF, false);
    u32 ohi = (u32)__builtin_amdgcn_update_dpp(-1, (int)hi, CTRL, 0xF, 0xF, false);
    u64 o = ((u64)ohi << 32) | olo;
    return o < m ? o : m;
}

// Full-wave u64 min, broadcast to all lanes of this wave.
__device__ __forceinline__ u64 wave_min_u64(u64 m) {
    m = dpp_min_step<0x111>(m); // row_shr:1
    m = dpp_min_step<0x112>(m); // row_shr:2
    m = dpp_min_step<0x114>(m); // row_shr:4
    m = dpp_min_step<0x118>(m); // row_shr:8
    m = dpp_min_step<0x142>(m); // row_bcast15
    m = dpp_min_step<0x143>(m); // row_bcast31
    u32 lo = (u32)__builtin_amdgcn_readlane((int)(u32)m, 63);
    u32 hi = (u32)__builtin_amdgcn_readlane((int)(u32)(m >> 32), 63);
    return ((u64)hi << 32) | lo;
}

__global__ void gather_k(const float* __restrict__ S1, const float* __restrict__ S2,
                         const int* __restrict__ idx,
                         float4* __restrict__ s1g, float4* __restrict__ s2g,
                         int* __restrict__ cnt) {
    int t = blockIdx.x * blockDim.x + threadIdx.x;
    if (t == 0) *cnt = 0;   // reset last-block counter each replay (stream-ordered)
    if (t >= BATCH * NS) return;
    int b = t >> 10;
    int j = idx[t];
    const float* p1 = S1 + ((size_t)b * NPTS + j) * 3;
    const float* p2 = S2 + ((size_t)b * NPTS + j) * 3;
    s1g[t] = make_float4(p1[0], p1[1], p1[2], 0.f);
    s2g[t] = make_float4(p2[0], p2[1], p2[2], 0.f);
}

// 1024-thread blocks: 16 waves share ONE staged pts tile (16 tasks/stage).
// One wave per (batch,row) [first half] or (batch,col) [second half]:
// sorted top-KD lists, transposed [KD][NS] per batch.
__global__ void __launch_bounds__(1024, 1)
lists_k(const float4* __restrict__ s1g, const float4* __restrict__ s2g,
        u64* __restrict__ rlist_g, u64* __restrict__ clist_g) {
    __shared__ float4 pts[NS];   // 16 KiB
    int gg = blockIdx.x * 16 + (threadIdx.x >> 6);
    int lane = threadIdx.x & 63;
    int side = (gg >= BATCH * NS) ? 1 : 0;   // 0 = rows over cols, 1 = cols over rows
    int g = gg - side * (BATCH * NS);
    int b = g >> 10;            // block-uniform (16 | 1024)
    u32 rc = (u32)(g & 1023);
    const float4* other = (side ? s1g : s2g) + (size_t)b * NS;
    pts[threadIdx.x] = other[threadIdx.x];   // one coalesced float4 per thread
    float4 a = side ? s2g[g] : s1g[g];
    __syncthreads();
    u64 cand[16];
    #pragma unroll
    for (int k = 0; k < 16; ++k) {
        int o = lane + (k << 6);
        float4 q = pts[o];
        float d = pdist3(a.x, a.y, a.z, q.x, q.y, q.z);
        cand[k] = side ? packv(d, (u32)o, rc) : packv(d, rc, (u32)o);
    }
    u64* out = (side ? clist_g : rlist_g) + (size_t)b * NS * KD + rc;
    for (int i = 0; i < KD; ++i) {
        u64 m1 = wave_min_u64(tree16(cand));
        if (lane == 0) out[(size_t)i * NS] = m1;   // [KD][NS] transposed
        #pragma unroll
        for (int k = 0; k < 16; ++k) cand[k] = (cand[k] == m1) ? DEADV : cand[k];
    }
}

// One 1024-thread block per batch. Parallel greedy via mutual minima.
// = r16 (best, 155 us resolve) + ONE isolated change: D's rescan scan is
// BATCHED 8-wide (all 8 index loads issue, then all 8 coord loads, then the
// ALU fold) -- the r13 batched-pop pattern applied to D's dependent-load
// chain. Clamped lanes read slot 0 and contribute DEADV (never win); fold
// order unchanged -> bit-exact. Phase profiler retained.
__global__ void __launch_bounds__(1024, 1)
resolve_k(const float4* __restrict__ s1g, const float4* __restrict__ s2g,
          const u64* __restrict__ rlist_gl, const u64* __restrict__ clist_gl,
          float* __restrict__ loss_ws, int* __restrict__ cnt,
          float* __restrict__ out, u64* __restrict__ instr) {
    __shared__ u64 rlist[KD * NS];   // 48 KiB  [KD][NS]
    __shared__ u64 clist[KD * NS];   // 48 KiB
    __shared__ u64 rmin[NS];         // 8 KiB
    __shared__ u64 cmin[NS];         // 8 KiB
    __shared__ float4 s1p[NS];       // 16 KiB (.x==NaN marks dead)
    __shared__ float4 s2p[NS];       // 16 KiB
    __shared__ u8 rptrs[NS], cptrs[NS];              // 2 KiB
    __shared__ u16 qrow[NS], qcol[NS];               // 4 KiB
    __shared__ u16 lrows[NS], lcols[NS];             // 4 KiB (stale-superset live sets)
    __shared__ float lred[1024];                     // 4 KiB
    __shared__ int qrn, qcn, matched, nlr, nlc, stale_n;
    int b = blockIdx.x;
    int tid = threadIdx.x;
    int lane = tid & 63, wv = tid >> 6;

    {   // coalesced list copies (1536 float4 each; layout-agnostic linear copy)
        const float4* rs = (const float4*)(rlist_gl + (size_t)b * NS * KD);
        const float4* cs = (const float4*)(clist_gl + (size_t)b * NS * KD);
        float4* rd = (float4*)rlist;
        float4* cd = (float4*)clist;
        for (int i = tid; i < NS * KD / 2; i += 1024) { rd[i] = rs[i]; cd[i] = cs[i]; }
    }
    s1p[tid] = s1g[(size_t)b * NS + tid];
    s2p[tid] = s2g[(size_t)b * NS + tid];
    rptrs[tid] = 1; cptrs[tid] = 1;
    lrows[tid] = (u16)tid; lcols[tid] = (u16)tid;
    if (tid == 0) { matched = 0; stale_n = NS; }
    __syncthreads();
    u64 rmin_reg = rlist[tid];       // head = [0][tid]; register copy stays valid
    rmin[tid] = rmin_reg;
    cmin[tid] = clist[tid];
    float loss = 0.f;
    __syncthreads();

    // phase-profiler state (thread 0 only; registers)
    long long tmark = 0;
    u64 sA = 0, sB = 0;
    if (tid == 0) tmark = clock64();

    for (int round = 0; round < NS; ++round) {
        // ---- A+B fused: mutual detection + kills (race-free, round-7 proof) ----
        u64 myk = rmin_reg;
        u32 c = (u32)myk & 1023u;
        bool mut = (myk != DEADV) && (cmin[c] == myk);
        if (mut) {
            loss += __uint_as_float((u32)(myk >> 20));
            rmin_reg = DEADV;
            rmin[tid] = DEADV;
            cmin[c] = DEADV;
            s1p[tid].x = __uint_as_float(QNANB);
            s2p[c].x   = __uint_as_float(QNANB);
        }
        u64 bal = __ballot((int)mut);
        if (lane == 0 && bal) atomicAdd(&matched, (int)__popcll(bal));
        if (tid == 0) { qrn = 0; qcn = 0; nlr = 0; nlc = 0; }
        __syncthreads();
        if (tid == 0) { long long t = clock64(); sA += (u64)(t - tmark); tmark = t; }
        int m = matched;
        if (m >= NS) break;
        int live = NS - m;
        int stale = stale_n;
        bool rebuild = (stale * 4 > live * 5 + 64);   // block-uniform
        // ---- C: BATCHED pop repair -- all slots + liveness loaded in parallel ----
        bool needR = false, needC = false;
        u64 rk = rmin_reg;
        if (rk != DEADV) {
            float pr = s2p[(u32)rk & 1023u].x;
            if (pr != pr) {
                int p0 = rptrs[tid];
                u64 e[KD];
                float lx[KD];
                #pragma unroll
                for (int p = 0; p < KD; ++p) e[p] = rlist[p * NS + tid];
                #pragma unroll
                for (int p = 0; p < KD; ++p) lx[p] = s2p[(u32)e[p] & 1023u].x;
                int sel = KD;
                #pragma unroll
                for (int p = KD - 1; p >= 1; --p) {   // slot 0 never >= rptr (>=1)
                    bool ok = (p >= p0) && (e[p] != DEADV) && (lx[p] == lx[p]);
                    sel = ok ? p : sel;
                }
                if (sel < KD) {
                    rmin_reg = e[sel];
                    rmin[tid] = e[sel];
                    rptrs[tid] = (u8)(sel + 1);
                } else {
                    rptrs[tid] = (u8)KD;
                    needR = true;
                }
            }
        }
        u64 ck = cmin[tid];
        if (ck != DEADV) {
            float pr = s1p[((u32)ck >> 10) & 1023u].x;
            if (pr != pr) {
                int p0 = cptrs[tid];
                u64 e[KD];
                float lx[KD];
                #pragma unroll
                for (int p = 0; p < KD; ++p) e[p] = clist[p * NS + tid];
                #pragma unroll
                for (int p = 0; p < KD; ++p) lx[p] = s1p[((u32)e[p] >> 10) & 1023u].x;
                int sel = KD;
                #pragma unroll
                for (int p = KD - 1; p >= 1; --p) {
                    bool ok = (p >= p0) && (e[p] != DEADV) && (lx[p] == lx[p]);
                    sel = ok ? p : sel;
                }
                if (sel < KD) {
                    cmin[tid] = e[sel];
                    cptrs[tid] = (u8)(sel + 1);
                } else {
                    cptrs[tid] = (u8)KD;
                    needC = true;
                }
            }
        }
        // ---- BALLOT ENQUEUE: one LDS atomic per wave, not per entry ----
        {
            u64 rb2 = __ballot((int)needR);
            if (rb2) {
                int rrank = (int)__popcll(rb2 & ((1ull << lane) - 1ull));
                int rbase = 0;
                if (lane == 0) rbase = atomicAdd(&qrn, (int)__popcll(rb2));
                rbase = __shfl(rbase, 0, 64);
                if (needR) qrow[rbase + rrank] = (u16)tid;
            }
            u64 cb2 = __ballot((int)needC);
            if (cb2) {
                int crank = (int)__popcll(cb2 & ((1ull << lane) - 1ull));
                int cbase = 0;
                if (lane == 0) cbase = atomicAdd(&qcn, (int)__popcll(cb2));
                cbase = __shfl(cbase, 0, 64);
                if (needC) qcol[cbase + crank] = (u16)tid;
            }
        }
        // ---- C2: LAZY compaction (only when stale list >1.25x live) ----
        if (rebuild) {
            float cx = s2p[tid].x;
            bool calive = (cx == cx);
            u64 cb = __ballot((int)calive);
            int crank = (int)__popcll(cb & ((1ull << lane) - 1ull));
            int cbase = 0;
            if (lane == 0) cbase = atomicAdd(&nlc, (int)__popcll(cb));
            cbase = __shfl(cbase, 0, 64);
            if (calive) lcols[cbase + crank] = (u16)tid;

            float rx = s1p[tid].x;
            bool ralive = (rx == rx);
            u64 rb = __ballot((int)ralive);
            int rrank = (int)__popcll(rb & ((1ull << lane) - 1ull));
            int rbase = 0;
            if (lane == 0) rbase = atomicAdd(&nlr, (int)__popcll(rb));
            rbase = __shfl(rbase, 0, 64);
            if (ralive) lrows[rbase + rrank] = (u16)tid;
        }
        __syncthreads();
        if (tid == 0) { long long t = clock64(); sB += (u64)(t - tmark); tmark = t; }
        int nr = qrn, nc = qcn;
        int scan_n = rebuild ? live : stale;   // live rows == live cols == NS - matched
        if (rebuild && tid == 0) stale_n = live;  // consumed next round (post-barrier)
        // ---- D: MERGED rescan queue; BATCHED 8-wide scan, top-2 refill ----
        int tot = nr + nc;
        for (int qi = wv; qi < tot; qi += 16) {
            if (qi < nr) {
                u32 r = qrow[qi];
                float4 a = s1p[r];
                u64 m1 = DEADV, m2 = DEADV;
                for (int base = 0; base < scan_n; base += 512) {
                    int ix[8]; float4 q[8]; bool ok[8];
                    #pragma unroll
                    for (int k = 0; k < 8; ++k) {
                        int i = base + lane + (k << 6);
                        ok[k] = i < scan_n;
                        ix[k] = lcols[ok[k] ? i : 0];    // 8 independent u16 loads
                    }
                    #pragma unroll
                    for (int k = 0; k < 8; ++k) q[k] = s2p[ix[k]];   // 8 independent b128
                    #pragma unroll
                    for (int k = 0; k < 8; ++k) {
                        float d = pdist3(a.x, a.y, a.z, q[k].x, q[k].y, q[k].z);
                        u64 p = ok[k] ? packv(d, r, (u32)ix[k]) : DEADV;
                        u64 mx = u64max2(p, m1);
                        m1 = u64min2(m1, p);
                        m2 = u64min2(m2, mx);
                    }
                }
                u64 M1 = wave_min_u64(m1);
                u64 c2 = (m1 == M1) ? m2 : m1;     // unique keys: one lane holds M1
                u64 M2 = wave_min_u64(c2);
                if (lane == 0) {
                    rmin[r] = M1;
                    rlist[(KD - 1) * NS + r] = M2; // refill tail (liveness-checked on pop)
                    rptrs[r] = KD - 1;
                }
            } else {
                u32 cc = qcol[qi - nr];
                float4 a = s2p[cc];
                u64 m1 = DEADV, m2 = DEADV;
                for (int base = 0; base < scan_n; base += 512) {
                    int ix[8]; float4 q[8]; bool ok[8];
                    #pragma unroll
                    for (int k = 0; k < 8; ++k) {
                        int i = base + lane + (k << 6);
                        ok[k] = i < scan_n;
                        ix[k] = lrows[ok[k] ? i : 0];
                    }
                    #pragma unroll
                    for (int k = 0; k < 8; ++k) q[k] = s1p[ix[k]];
                    #pragma unroll
                    for (int k = 0; k < 8; ++k) {
                        float d = pdist3(q[k].x, q[k].y, q[k].z, a.x, a.y, a.z);
                        u64 p = ok[k] ? packv(d, (u32)ix[k], cc) : DEADV;
                        u64 mx = u64max2(p, m1);
                        m1 = u64min2(m1, p);
                        m2 = u64min2(m2, mx);
                    }
                }
                u64 M1 = wave_min_u64(m1);
                u64 c2 = (m1 == M1) ? m2 : m1;
                u64 M2 = wave_min_u64(c2);
                if (lane == 0) {
                    cmin[cc] = M1;
                    clist[(KD - 1) * NS + cc] = M2;
                    cptrs[cc] = KD - 1;
                }
            }
        }
        __syncthreads();
        if (needR) rmin_reg = rmin[tid];   // D's lane0 refreshed our row's head
        if (tid == 0) tmark = clock64();   // D segment implied by subtraction
    }

    // phase-profile emission: block 0, thread 0; radix-64 in store count
    if (instr && b == 0 && tid == 0) {
        u64 n1 = sA >> 13; if (n1 > 63) n1 = 63;
        u64 n2 = sB >> 13; if (n2 > 63) n2 = 63;
        int n = (int)(n1 * 64 + n2);
        for (int k = 0; k < n; ++k)
            __builtin_nontemporal_store(0ull, instr + (size_t)k * 8);
    }

    // deterministic block reduction of per-thread losses (order preserved bit-exactly)
    lred[tid] = loss;
    __syncthreads();
    #pragma unroll
    for (int s = 512; s > 0; s >>= 1) {
        if (tid < s) lred[tid] += lred[tid + s];
        __syncthreads();
    }
    if (tid == 0) {
        atomicExch(&loss_ws[b], lred[0] * (1.0f / NS));  // device-scope publish
        __threadfence();
        int old = atomicAdd(cnt, 1);
        if (old == BATCH - 1) {            // last block: deterministic fixed-order sum
            __threadfence();
            float s = 0.f;
            for (int i = 0; i < BATCH; ++i) s += atomicAdd(&loss_ws[i], 0.0f);
            out[0] = s * (1.0f / BATCH);
        }
    }
}

extern "C" void kernel_launch(void* const* d_in, const int* in_sizes, int n_in,
                              void* d_out, int out_size, void* d_ws, size_t ws_size,
                              hipStream_t stream) {
    const float* S1 = (const float*)d_in[0];
    const float* S2 = (const float*)d_in[1];
    const int* idx  = (const int*)d_in[2];
    char* ws = (char*)d_ws;
    size_t o = 0;
    float4* s1g    = (float4*)(ws + o); o += (size_t)BATCH * NS * 16;
    float4* s2g    = (float4*)(ws + o); o += (size_t)BATCH * NS * 16;
    u64* rlist_g   = (u64*)(ws + o);    o += (size_t)BATCH * NS * KD * 8;
    u64* clist_g   = (u64*)(ws + o);    o += (size_t)BATCH * NS * KD * 8;
    float* loss_ws = (float*)(ws + o);  o += (size_t)BATCH * 4;
    int* cnt       = (int*)(ws + o);    o += 64;
    o = (o + 4095) & ~(size_t)4095;     // align
    u64* instr     = (u64*)(ws + o);
    o += (size_t)4096 * 64;             // up to 4095 distinct 64B lines (256 KiB)
    u64* instr_p = (ws_size >= o) ? instr : (u64*)0;

    gather_k<<<(BATCH * NS + 255) / 256, 256, 0, stream>>>(S1, S2, idx, s1g, s2g, cnt);
    lists_k<<<2 * BATCH * NS / 16, 1024, 0, stream>>>(s1g, s2g, rlist_g, clist_g);
    resolve_k<<<BATCH, 1024, 0, stream>>>(s1g, s2g, rlist_g, clist_g, loss_ws, cnt,
                                          (float*)d_out, instr_p);
}

// Round 18
// 190.231 us; speedup vs baseline: 1.2608x; 1.2608x over previous
//
#include <hip/hip_runtime.h>
#include <stdint.h>

#define BATCH 8
#define NPTS 4096
#define NS 1024
#define KD 6   // sorted-list depth (rows and cols)

typedef unsigned long long u64;
typedef unsigned int u32;
typedef unsigned short u16;
typedef unsigned char u8;

#define DEADV (~0ull)
#define QNANB 0x7FC00000u
// key: [51:20]=f32 dist bits, [19:10]=row, [9:0]=col. u64 order == (dist,row,col)
// lexicographic == JAX row-major argmin tie-break. Keys unique per (row,col).
// NaN dist bits sort above all finite distances -> dead coords auto-lose.

__device__ __forceinline__ float pdist3(float ax, float ay, float az,
                                        float bx, float by, float bz) {
    float dx = ax - bx, dy = ay - by, dz = az - bz;
    float d2 = __fmaf_rn(dz, dz, __fmaf_rn(dy, dy, dx * dx));
    return __fsqrt_rn(d2);
}

__device__ __forceinline__ u64 packv(float d, u32 row, u32 col) {
    return ((u64)__float_as_uint(d) << 20) | ((u64)row << 10) | (u64)col;
}

__device__ __forceinline__ u64 u64min2(u64 a, u64 b) { return a < b ? a : b; }
__device__ __forceinline__ u64 u64max2(u64 a, u64 b) { return a > b ? a : b; }

__device__ __forceinline__ u64 tree16(const u64* p) {
    u64 a0 = u64min2(p[0], p[1]),   a1 = u64min2(p[2], p[3]);
    u64 a2 = u64min2(p[4], p[5]),   a3 = u64min2(p[6], p[7]);
    u64 a4 = u64min2(p[8], p[9]),   a5 = u64min2(p[10], p[11]);
    u64 a6 = u64min2(p[12], p[13]), a7 = u64min2(p[14], p[15]);
    u64 b0 = u64min2(a0, a1), b1 = u64min2(a2, a3);
    u64 b2 = u64min2(a4, a5), b3 = u64min2(a6, a7);
    return u64min2(u64min2(b0, b1), u64min2(b2, b3));
}

template<int CTRL>
__device__ __forceinline__ u64 dpp_min_step(u64 m) {
    u32 lo = (u32)m, hi = (u32)(m >> 32);
    u32 olo = (u32)__builtin_amdgcn_update_dpp(-1, (int)lo, CTRL, 0xF, 0xF, false);
    u32 ohi = (u32)__builtin_amdgcn_update_dpp(-1, (int)hi, CTRL, 0xF, 0xF, false);
    u64 o = ((u64)ohi << 32) | olo;
    return o < m ? o : m;
}

// Full-wave u64 min, broadcast to all lanes of this wave.
__device__ __forceinline__ u64 wave_min_u64(u64 m) {
    m = dpp_min_step<0x111>(m); // row_shr:1
    m = dpp_min_step<0x112>(m); // row_shr:2
    m = dpp_min_step<0x114>(m); // row_shr:4
    m = dpp_min_step<0x118>(m); // row_shr:8
    m = dpp_min_step<0x142>(m); // row_bcast15
    m = dpp_min_step<0x143>(m); // row_bcast31
    u32 lo = (u32)__builtin_amdgcn_readlane((int)(u32)m, 63);
    u32 hi = (u32)__builtin_amdgcn_readlane((int)(u32)(m >> 32), 63);
    return ((u64)hi << 32) | lo;
}

__global__ void gather_k(const float* __restrict__ S1, const float* __restrict__ S2,
                         const int* __restrict__ idx,
                         float4* __restrict__ s1g, float4* __restrict__ s2g,
                         int* __restrict__ cnt) {
    int t = blockIdx.x * blockDim.x + threadIdx.x;
    if (t == 0) *cnt = 0;   // reset last-block counter each replay (stream-ordered)
    if (t >= BATCH * NS) return;
    int b = t >> 10;
    int j = idx[t];
    const float* p1 = S1 + ((size_t)b * NPTS + j) * 3;
    const float* p2 = S2 + ((size_t)b * NPTS + j) * 3;
    s1g[t] = make_float4(p1[0], p1[1], p1[2], 0.f);
    s2g[t] = make_float4(p2[0], p2[1], p2[2], 0.f);
}

// 1024-thread blocks: 16 waves share ONE staged pts tile (16 tasks/stage).
// One wave per (batch,row) [first half] or (batch,col) [second half]:
// sorted top-KD lists, transposed [KD][NS] per batch.
__global__ void __launch_bounds__(1024, 1)
lists_k(const float4* __restrict__ s1g, const float4* __restrict__ s2g,
        u64* __restrict__ rlist_g, u64* __restrict__ clist_g) {
    __shared__ float4 pts[NS];   // 16 KiB
    int gg = blockIdx.x * 16 + (threadIdx.x >> 6);
    int lane = threadIdx.x & 63;
    int side = (gg >= BATCH * NS) ? 1 : 0;   // 0 = rows over cols, 1 = cols over rows
    int g = gg - side * (BATCH * NS);
    int b = g >> 10;            // block-uniform (16 | 1024)
    u32 rc = (u32)(g & 1023);
    const float4* other = (side ? s1g : s2g) + (size_t)b * NS;
    pts[threadIdx.x] = other[threadIdx.x];   // one coalesced float4 per thread
    float4 a = side ? s2g[g] : s1g[g];
    __syncthreads();
    u64 cand[16];
    #pragma unroll
    for (int k = 0; k < 16; ++k) {
        int o = lane + (k << 6);
        float4 q = pts[o];
        float d = pdist3(a.x, a.y, a.z, q.x, q.y, q.z);
        cand[k] = side ? packv(d, (u32)o, rc) : packv(d, rc, (u32)o);
    }
    u64* out = (side ? clist_g : rlist_g) + (size_t)b * NS * KD + rc;
    for (int i = 0; i < KD; ++i) {
        u64 m1 = wave_min_u64(tree16(cand));
        if (lane == 0) out[(size_t)i * NS] = m1;   // [KD][NS] transposed
        #pragma unroll
        for (int k = 0; k < 16; ++k) cand[k] = (cand[k] == m1) ? DEADV : cand[k];
    }
}

// One 1024-thread block per batch. Parallel greedy via mutual minima.
// FINAL form = r16 (best measured: 192.4 us total, 155 us resolve):
//  - A+B fused kill phase (barrier between detect/kill removable: keys
//    unique, only the winner's thread matches its col's cmin).
//  - C: batched parallel pop (all KD slots + liveness loaded independently,
//    ALU-select first live slot) -- cut the serial LDS chain ~5x.
//  - rmin[tid] register-cached (self-written-only; reload post-D on needR).
//  - transposed [KD][NS] lists -> stride-1 conflict-free walks.
//  - ballot enqueue (one LDS atomic per wave); merged row+col rescan queue.
//  - D: 64-lane strided scan over lazily-compacted live sets, running
//    top-2, two wave_min_u64 reductions, depth-2 refill.
// r17's 8-wide scan batching reverted (scratch spill); profiler removed.
__global__ void __launch_bounds__(1024, 1)
resolve_k(const float4* __restrict__ s1g, const float4* __restrict__ s2g,
          const u64* __restrict__ rlist_gl, const u64* __restrict__ clist_gl,
          float* __restrict__ loss_ws, int* __restrict__ cnt,
          float* __restrict__ out) {
    __shared__ u64 rlist[KD * NS];   // 48 KiB  [KD][NS]
    __shared__ u64 clist[KD * NS];   // 48 KiB
    __shared__ u64 rmin[NS];         // 8 KiB
    __shared__ u64 cmin[NS];         // 8 KiB
    __shared__ float4 s1p[NS];       // 16 KiB (.x==NaN marks dead)
    __shared__ float4 s2p[NS];       // 16 KiB
    __shared__ u8 rptrs[NS], cptrs[NS];              // 2 KiB
    __shared__ u16 qrow[NS], qcol[NS];               // 4 KiB
    __shared__ u16 lrows[NS], lcols[NS];             // 4 KiB (stale-superset live sets)
    __shared__ float lred[1024];                     // 4 KiB
    __shared__ int qrn, qcn, matched, nlr, nlc, stale_n;
    int b = blockIdx.x;
    int tid = threadIdx.x;
    int lane = tid & 63, wv = tid >> 6;

    {   // coalesced list copies (1536 float4 each; layout-agnostic linear copy)
        const float4* rs = (const float4*)(rlist_gl + (size_t)b * NS * KD);
        const float4* cs = (const float4*)(clist_gl + (size_t)b * NS * KD);
        float4* rd = (float4*)rlist;
        float4* cd = (float4*)clist;
        for (int i = tid; i < NS * KD / 2; i += 1024) { rd[i] = rs[i]; cd[i] = cs[i]; }
    }
    s1p[tid] = s1g[(size_t)b * NS + tid];
    s2p[tid] = s2g[(size_t)b * NS + tid];
    rptrs[tid] = 1; cptrs[tid] = 1;
    lrows[tid] = (u16)tid; lcols[tid] = (u16)tid;
    if (tid == 0) { matched = 0; stale_n = NS; }
    __syncthreads();
    u64 rmin_reg = rlist[tid];       // head = [0][tid]; register copy stays valid
    rmin[tid] = rmin_reg;
    cmin[tid] = clist[tid];
    float loss = 0.f;
    __syncthreads();

    for (int round = 0; round < NS; ++round) {
        // ---- A+B fused: mutual detection + kills (race-free, round-7 proof) ----
        u64 myk = rmin_reg;
        u32 c = (u32)myk & 1023u;
        bool mut = (myk != DEADV) && (cmin[c] == myk);
        if (mut) {
            loss += __uint_as_float((u32)(myk >> 20));
            rmin_reg = DEADV;
            rmin[tid] = DEADV;
            cmin[c] = DEADV;
            s1p[tid].x = __uint_as_float(QNANB);
            s2p[c].x   = __uint_as_float(QNANB);
        }
        u64 bal = __ballot((int)mut);
        if (lane == 0 && bal) atomicAdd(&matched, (int)__popcll(bal));
        if (tid == 0) { qrn = 0; qcn = 0; nlr = 0; nlc = 0; }
        __syncthreads();
        int m = matched;
        if (m >= NS) break;
        int live = NS - m;
        int stale = stale_n;
        bool rebuild = (stale * 4 > live * 5 + 64);   // block-uniform
        // ---- C: BATCHED pop repair -- all slots + liveness loaded in parallel ----
        bool needR = false, needC = false;
        u64 rk = rmin_reg;
        if (rk != DEADV) {
            float pr = s2p[(u32)rk & 1023u].x;
            if (pr != pr) {
                int p0 = rptrs[tid];
                u64 e[KD];
                float lx[KD];
                #pragma unroll
                for (int p = 0; p < KD; ++p) e[p] = rlist[p * NS + tid];
                #pragma unroll
                for (int p = 0; p < KD; ++p) lx[p] = s2p[(u32)e[p] & 1023u].x;
                int sel = KD;
                #pragma unroll
                for (int p = KD - 1; p >= 1; --p) {   // slot 0 never >= rptr (>=1)
                    bool ok = (p >= p0) && (e[p] != DEADV) && (lx[p] == lx[p]);
                    sel = ok ? p : sel;
                }
                if (sel < KD) {
                    rmin_reg = e[sel];
                    rmin[tid] = e[sel];
                    rptrs[tid] = (u8)(sel + 1);
                } else {
                    rptrs[tid] = (u8)KD;
                    needR = true;
                }
            }
        }
        u64 ck = cmin[tid];
        if (ck != DEADV) {
            float pr = s1p[((u32)ck >> 10) & 1023u].x;
            if (pr != pr) {
                int p0 = cptrs[tid];
                u64 e[KD];
                float lx[KD];
                #pragma unroll
                for (int p = 0; p < KD; ++p) e[p] = clist[p * NS + tid];
                #pragma unroll
                for (int p = 0; p < KD; ++p) lx[p] = s1p[((u32)e[p] >> 10) & 1023u].x;
                int sel = KD;
                #pragma unroll
                for (int p = KD - 1; p >= 1; --p) {
                    bool ok = (p >= p0) && (e[p] != DEADV) && (lx[p] == lx[p]);
                    sel = ok ? p : sel;
                }
                if (sel < KD) {
                    cmin[tid] = e[sel];
                    cptrs[tid] = (u8)(sel + 1);
                } else {
                    cptrs[tid] = (u8)KD;
                    needC = true;
                }
            }
        }
        // ---- BALLOT ENQUEUE: one LDS atomic per wave, not per entry ----
        {
            u64 rb2 = __ballot((int)needR);
            if (rb2) {
                int rrank = (int)__popcll(rb2 & ((1ull << lane) - 1ull));
                int rbase = 0;
                if (lane == 0) rbase = atomicAdd(&qrn, (int)__popcll(rb2));
                rbase = __shfl(rbase, 0, 64);
                if (needR) qrow[rbase + rrank] = (u16)tid;
            }
            u64 cb2 = __ballot((int)needC);
            if (cb2) {
                int crank = (int)__popcll(cb2 & ((1ull << lane) - 1ull));
                int cbase = 0;
                if (lane == 0) cbase = atomicAdd(&qcn, (int)__popcll(cb2));
                cbase = __shfl(cbase, 0, 64);
                if (needC) qcol[cbase + crank] = (u16)tid;
            }
        }
        // ---- C2: LAZY compaction (only when stale list >1.25x live) ----
        if (rebuild) {
            float cx = s2p[tid].x;
            bool calive = (cx == cx);
            u64 cb = __ballot((int)calive);
            int crank = (int)__popcll(cb & ((1ull << lane) - 1ull));
            int cbase = 0;
            if (lane == 0) cbase = atomicAdd(&nlc, (int)__popcll(cb));
            cbase = __shfl(cbase, 0, 64);
            if (calive) lcols[cbase + crank] = (u16)tid;

            float rx = s1p[tid].x;
            bool ralive = (rx == rx);
            u64 rb = __ballot((int)ralive);
            int rrank = (int)__popcll(rb & ((1ull << lane) - 1ull));
            int rbase = 0;
            if (lane == 0) rbase = atomicAdd(&nlr, (int)__popcll(rb));
            rbase = __shfl(rbase, 0, 64);
            if (ralive) lrows[rbase + rrank] = (u16)tid;
        }
        __syncthreads();
        int nr = qrn, nc = qcn;
        int scan_n = rebuild ? live : stale;   // live rows == live cols == NS - matched
        if (rebuild && tid == 0) stale_n = live;  // consumed next round (post-barrier)
        // ---- D: MERGED rescan queue over (stale) compact sets, top-2 refill ----
        int tot = nr + nc;
        for (int qi = wv; qi < tot; qi += 16) {
            if (qi < nr) {
                u32 r = qrow[qi];
                float4 a = s1p[r];
                u64 m1 = DEADV, m2 = DEADV;
                for (int i = lane; i < scan_n; i += 64) {
                    int cc = lcols[i];
                    float4 q = s2p[cc];                      // one ds_read_b128
                    float d = pdist3(a.x, a.y, a.z, q.x, q.y, q.z);
                    u64 p = packv(d, r, (u32)cc);            // dead -> NaN key, auto-loses
                    u64 mx = u64max2(p, m1);
                    m1 = u64min2(m1, p);
                    m2 = u64min2(m2, mx);
                }
                u64 M1 = wave_min_u64(m1);
                u64 c2 = (m1 == M1) ? m2 : m1;     // unique keys: one lane holds M1
                u64 M2 = wave_min_u64(c2);
                if (lane == 0) {
                    rmin[r] = M1;
                    rlist[(KD - 1) * NS + r] = M2; // refill tail (liveness-checked on pop)
                    rptrs[r] = KD - 1;
                }
            } else {
                u32 cc = qcol[qi - nr];
                float4 a = s2p[cc];
                u64 m1 = DEADV, m2 = DEADV;
                for (int i = lane; i < scan_n; i += 64) {
                    int r = lrows[i];
                    float4 q = s1p[r];
                    float d = pdist3(q.x, q.y, q.z, a.x, a.y, a.z);
                    u64 p = packv(d, (u32)r, cc);
                    u64 mx = u64max2(p, m1);
                    m1 = u64min2(m1, p);
                    m2 = u64min2(m2, mx);
                }
                u64 M1 = wave_min_u64(m1);
                u64 c2 = (m1 == M1) ? m2 : m1;
                u64 M2 = wave_min_u64(c2);
                if (lane == 0) {
                    cmin[cc] = M1;
                    clist[(KD - 1) * NS + cc] = M2;
                    cptrs[cc] = KD - 1;
                }
            }
        }
        __syncthreads();
        if (needR) rmin_reg = rmin[tid];   // D's lane0 refreshed our row's head
    }

    // deterministic block reduction of per-thread losses (order preserved bit-exactly)
    lred[tid] = loss;
    __syncthreads();
    #pragma unroll
    for (int s = 512; s > 0; s >>= 1) {
        if (tid < s) lred[tid] += lred[tid + s];
        __syncthreads();
    }
    if (tid == 0) {
        atomicExch(&loss_ws[b], lred[0] * (1.0f / NS));  // device-scope publish
        __threadfence();
        int old = atomicAdd(cnt, 1);
        if (old == BATCH - 1) {            // last block: deterministic fixed-order sum
            __threadfence();
            float s = 0.f;
            for (int i = 0; i < BATCH; ++i) s += atomicAdd(&loss_ws[i], 0.0f);
            out[0] = s * (1.0f / BATCH);
        }
    }
}

extern "C" void kernel_launch(void* const* d_in, const int* in_sizes, int n_in,
                              void* d_out, int out_size, void* d_ws, size_t ws_size,
                              hipStream_t stream) {
    const float* S1 = (const float*)d_in[0];
    const float* S2 = (const float*)d_in[1];
    const int* idx  = (const int*)d_in[2];
    char* ws = (char*)d_ws;
    size_t o = 0;
    float4* s1g    = (float4*)(ws + o); o += (size_t)BATCH * NS * 16;
    float4* s2g    = (float4*)(ws + o); o += (size_t)BATCH * NS * 16;
    u64* rlist_g   = (u64*)(ws + o);    o += (size_t)BATCH * NS * KD * 8;
    u64* clist_g   = (u64*)(ws + o);    o += (size_t)BATCH * NS * KD * 8;
    float* loss_ws = (float*)(ws + o);  o += (size_t)BATCH * 4;
    int* cnt       = (int*)(ws + o);

    gather_k<<<(BATCH * NS + 255) / 256, 256, 0, stream>>>(S1, S2, idx, s1g, s2g, cnt);
    lists_k<<<2 * BATCH * NS / 16, 1024, 0, stream>>>(s1g, s2g, rlist_g, clist_g);
    resolve_k<<<BATCH, 1024, 0, stream>>>(s1g, s2g, rlist_g, clist_g, loss_ws, cnt,
                                          (float*)d_out);
}